// Round 3
// baseline (1358.091 us; speedup 1.0000x reference)
//
#include <hip/hip_runtime.h>
#include <hip/hip_bf16.h>

// PhraseClassifier R3: algebraic restructure. z_pre is linear in hidden, so:
//   proj_gemm:  U[r]=h[r,0:512]@W1_top, V[r]=h[r,512:]@W1_bot  (dense MFMA GEMM)
//   span_eval:  z=relu(U[e-1]-U[b-1]+V[b]-V[e]+b1); logit=z.W2; BCE reduce
// This cuts GEMM FLOPs 8x (row reuse) and turns the random gather into
// contiguous 1KB row reads of an L3-resident 33.6MB UV matrix.

typedef float f32x4 __attribute__((ext_vector_type(4)));
typedef __bf16 bf16x8 __attribute__((ext_vector_type(8)));

__device__ __forceinline__ unsigned short f2bf(float f) {
  unsigned int u = __float_as_uint(f);
  u += 0x7fffu + ((u >> 16) & 1u);   // RNE
  return (unsigned short)(u >> 16);
}

// ---------------- prep: W1 [1024][512] fp32 -> W1t [512][1024] bf16 ----------------
__global__ void w1_transpose(const float* __restrict__ W1, unsigned short* __restrict__ W1t) {
  __shared__ float tile[32][33];
  int k0 = blockIdx.x * 32, n0 = blockIdx.y * 32;
  int tx = threadIdx.x, ty = threadIdx.y;  // 32 x 8
#pragma unroll
  for (int r = 0; r < 4; ++r)
    tile[ty + r * 8][tx] = W1[(k0 + ty + r * 8) * 512 + n0 + tx];
  __syncthreads();
#pragma unroll
  for (int r = 0; r < 4; ++r)
    W1t[(n0 + ty + r * 8) * 1024 + k0 + tx] = f2bf(tile[tx][ty + r * 8]);
}

// ---------------- proj_gemm: UV[r][h*512+n] = sum_k h[r][h*512+k]*W1[h*512+k][n] ----
// Tile 128(M)x128(N), K=512 (16 iters of BK=32). 4 waves; wave w owns M rows
// [w*32,w*32+32): 2x8 MFMA tiles. Single-buffer 2-barrier (m97 shape).
__global__ __launch_bounds__(256, 2) void proj_gemm(
    const float* __restrict__ hidden,        // [16384][1024]
    const unsigned short* __restrict__ w1t,  // [512][1024] bf16 (W1 transposed)
    unsigned short* __restrict__ UV) {       // [16384][1024] bf16
  __shared__ __align__(16) unsigned short Ab[128 * 40];  // +8 pad
  __shared__ __align__(16) unsigned short Bb[128 * 32];  // XOR chunk-swizzled
  const int t = threadIdx.x;
  const int lane = t & 63;
  const int w = t >> 6;
  const int r0 = blockIdx.x << 7;
  const int n0 = blockIdx.y << 7;
  const int hk = blockIdx.z << 9;   // half k-base (0 or 512)

  f32x4 acc[2][8];
#pragma unroll
  for (int i = 0; i < 2; ++i)
#pragma unroll
    for (int j = 0; j < 8; ++j) acc[i][j] = (f32x4){0.f, 0.f, 0.f, 0.f};

  const int ar = t >> 1;            // A stage row 0..127
  const int akc = (t & 1) << 4;     // k offset 0/16
  const float* agp = hidden + (r0 + ar) * 1024 + hk + akc;

  // B global offsets: LDS slot chunk c holds logical chunk c^((n>>1)&3)
  int boff[2];
#pragma unroll
  for (int q = 0; q < 2; ++q) {
    int ln = (w << 5) + (q << 4) + (lane >> 2);
    int sc = (lane & 3) ^ ((ln >> 1) & 3);
    boff[q] = (n0 + ln) * 1024 + hk + (sc << 3);
  }

  for (int it = 0; it < 16; ++it) {
    const int k0 = it << 5;
#pragma unroll
    for (int q = 0; q < 2; ++q) {
      const unsigned short* gp = w1t + boff[q] + k0;
      unsigned short* lp = &Bb[((w << 5) + (q << 4)) << 5];  // wave-uniform
      __builtin_amdgcn_global_load_lds(
          (const __attribute__((address_space(1))) void*)gp,
          (__attribute__((address_space(3))) void*)lp, 16, 0, 0);
    }
    {
      const float4* p = (const float4*)(agp + k0);
      float4 a0 = p[0], a1 = p[1], a2 = p[2], a3 = p[3];
      uint4 p0, p1;
      p0.x = (unsigned)f2bf(a0.x) | ((unsigned)f2bf(a0.y) << 16);
      p0.y = (unsigned)f2bf(a0.z) | ((unsigned)f2bf(a0.w) << 16);
      p0.z = (unsigned)f2bf(a1.x) | ((unsigned)f2bf(a1.y) << 16);
      p0.w = (unsigned)f2bf(a1.z) | ((unsigned)f2bf(a1.w) << 16);
      p1.x = (unsigned)f2bf(a2.x) | ((unsigned)f2bf(a2.y) << 16);
      p1.y = (unsigned)f2bf(a2.z) | ((unsigned)f2bf(a2.w) << 16);
      p1.z = (unsigned)f2bf(a3.x) | ((unsigned)f2bf(a3.y) << 16);
      p1.w = (unsigned)f2bf(a3.z) | ((unsigned)f2bf(a3.w) << 16);
      *(uint4*)((char*)Ab + ar * 80 + akc * 2) = p0;
      *(uint4*)((char*)Ab + ar * 80 + akc * 2 + 16) = p1;
    }
    __syncthreads();

    bf16x8 af[2], bfr[8];
#pragma unroll
    for (int mt = 0; mt < 2; ++mt) {
      int row = (w << 5) + (mt << 4) + (lane & 15);
      af[mt] = *(const bf16x8*)((const char*)Ab + row * 80 + ((lane >> 4) << 4));
    }
#pragma unroll
    for (int nt = 0; nt < 8; ++nt) {
      int ln = (nt << 4) + (lane & 15);
      int cs = (lane >> 4) ^ ((ln >> 1) & 3);
      bfr[nt] = *(const bf16x8*)((const char*)Bb + ln * 64 + (cs << 4));
    }
#pragma unroll
    for (int mt = 0; mt < 2; ++mt)
#pragma unroll
      for (int nt = 0; nt < 8; ++nt)
        acc[mt][nt] = __builtin_amdgcn_mfma_f32_16x16x32_bf16(af[mt], bfr[nt],
                                                              acc[mt][nt], 0, 0, 0);
    __syncthreads();
  }

  // C/D layout: col = lane&15, row = (lane>>4)*4 + reg  [m89/m91]
#pragma unroll
  for (int mt = 0; mt < 2; ++mt)
#pragma unroll
    for (int r = 0; r < 4; ++r) {
      int row = r0 + (w << 5) + (mt << 4) + ((lane >> 4) << 2) + r;
#pragma unroll
      for (int nt = 0; nt < 8; ++nt) {
        int col = n0 + (nt << 4) + (lane & 15);
        UV[row * 1024 + hk + col] = f2bf(acc[mt][nt][r]);
      }
    }
}

// ---------------- span_eval: one wave per span ----------------
__global__ void span_eval(const unsigned short* __restrict__ UV,
                          const int* __restrict__ bids, const int* __restrict__ begins,
                          const int* __restrict__ ends, const int* __restrict__ flags,
                          const float* __restrict__ weights,
                          const float* __restrict__ b1, const float* __restrict__ w2,
                          const float* __restrict__ b2,
                          float* __restrict__ wsf, int* __restrict__ wsi) {
  __shared__ float redp[4], redn[4];
  __shared__ int redc[4];
  const int t = threadIdx.x;
  const int lane = t & 63;
  const int w = t >> 6;
  const int s = (blockIdx.x << 2) + w;

  int b = bids[s], bg = begins[s], en = ends[s];
  const int c0 = lane << 3;
  bf16x8 u1 = *(const bf16x8*)(UV + ((((en - 1) << 5) + b) << 10) + c0);
  bf16x8 u0 = *(const bf16x8*)(UV + ((((bg - 1) << 5) + b) << 10) + c0);
  bf16x8 vb = *(const bf16x8*)(UV + (((bg << 5) + b) << 10) + 512 + c0);
  bf16x8 ve = *(const bf16x8*)(UV + (((en << 5) + b) << 10) + 512 + c0);
  float4 b1a = *(const float4*)(b1 + c0), b1b = *(const float4*)(b1 + c0 + 4);
  float4 w2a = *(const float4*)(w2 + c0), w2b = *(const float4*)(w2 + c0 + 4);
  float b1v[8] = {b1a.x, b1a.y, b1a.z, b1a.w, b1b.x, b1b.y, b1b.z, b1b.w};
  float w2v[8] = {w2a.x, w2a.y, w2a.z, w2a.w, w2b.x, w2b.y, w2b.z, w2b.w};

  float sv = 0.f;
#pragma unroll
  for (int j = 0; j < 8; ++j) {
    float zp = (float)u1[j] - (float)u0[j] + (float)vb[j] - (float)ve[j] + b1v[j];
    sv += fmaxf(zp, 0.f) * w2v[j];
  }
#pragma unroll
  for (int off = 1; off < 64; off <<= 1) sv += __shfl_xor(sv, off);

  if (lane == 0) {
    float logit = sv + b2[0];
    float p = 1.f / (1.f + expf(-logit));
    p = fminf(fmaxf(p, 1e-7f), 1.f - 1e-7f);
    int fl = flags[s];
    float bce = (fl == 1) ? -logf(p) : -logf(1.f - p);
    float term = weights[s] * bce;
    redp[w] = (fl == 1) ? term : 0.f;
    redn[w] = (fl == 1) ? 0.f : term;
    redc[w] = (fl == 1) ? 1 : 0;
  }
  __syncthreads();
  if (t == 0) {
    atomicAdd(&wsf[0], redp[0] + redp[1] + redp[2] + redp[3]);
    atomicAdd(&wsf[1], redn[0] + redn[1] + redn[2] + redn[3]);
    atomicAdd(&wsi[2], redc[0] + redc[1] + redc[2] + redc[3]);
  }
}

// ---------------- finalize ----------------
__global__ void finalize(const float* __restrict__ wsf, const int* __restrict__ wsi,
                         float* __restrict__ out, int nspans) {
  float pos = wsf[0], neg = wsf[1];
  float scale = 2.f * (float)wsi[2] / (float)nspans;
  out[0] = (pos + scale * neg) / (float)nspans;
}

extern "C" void kernel_launch(void* const* d_in, const int* in_sizes, int n_in,
                              void* d_out, int out_size, void* d_ws, size_t ws_size,
                              hipStream_t stream) {
  const float* hidden = (const float*)d_in[0];
  const int* bids     = (const int*)d_in[1];
  const int* begins   = (const int*)d_in[2];
  const int* ends     = (const int*)d_in[3];
  const int* flags    = (const int*)d_in[4];
  const float* weights = (const float*)d_in[5];
  const float* W1 = (const float*)d_in[6];
  const float* b1 = (const float*)d_in[7];
  const float* W2 = (const float*)d_in[8];
  const float* b2 = (const float*)d_in[9];
  float* out = (float*)d_out;
  const int nspans = in_sizes[1];  // 131072

  float* wsf = (float*)d_ws;                                        // [0]=pos,[1]=neg
  int* wsi = (int*)d_ws;                                            // [2]=npos
  unsigned short* W1t = (unsigned short*)((char*)d_ws + 256);       // 1 MiB
  unsigned short* UV = (unsigned short*)((char*)d_ws + (2 << 20));  // 33.6 MiB

  hipMemsetAsync(d_ws, 0, 256, stream);

  w1_transpose<<<dim3(32, 16), dim3(32, 8), 0, stream>>>(W1, W1t);
  proj_gemm<<<dim3(128, 4, 2), 256, 0, stream>>>(hidden, W1t, UV);
  span_eval<<<nspans / 4, 256, 0, stream>>>(UV, bids, begins, ends, flags, weights,
                                            b1, W2, b2, wsf, wsi);
  finalize<<<1, 1, 0, stream>>>(wsf, wsi, out, nspans);
}

// Round 4
// 219.824 us; speedup vs baseline: 6.1781x; 6.1781x over previous
//
#include <hip/hip_runtime.h>
#include <hip/hip_bf16.h>

// PhraseClassifier R4. Same algebra as R3 (z_pre linear in hidden):
//   proj_gemm: U[r]=h[r,:512]@W1_top, V[r]=h[r,512:]@W1_bot (MFMA, LDS-repacked stores)
//   span_eval: z=relu(U[e-1]-U[b-1]+V[b]-V[e]+b1); logit=z.W2; BCE
// R4 fixes R3's collapse: NO global atomics (per-block partials + finalize),
// 16 spans/wave with 2-span load pipeline, coalesced proj_gemm epilogue.

typedef float f32x4 __attribute__((ext_vector_type(4)));
typedef __bf16 bf16x8 __attribute__((ext_vector_type(8)));

__device__ __forceinline__ unsigned short f2bf(float f) {
  unsigned int u = __float_as_uint(f);
  u += 0x7fffu + ((u >> 16) & 1u);   // RNE
  return (unsigned short)(u >> 16);
}

// ---------------- prep: W1 [1024][512] fp32 -> W1t [512][1024] bf16 ----------------
__global__ void w1_transpose(const float* __restrict__ W1, unsigned short* __restrict__ W1t) {
  __shared__ float tile[32][33];
  int k0 = blockIdx.x * 32, n0 = blockIdx.y * 32;
  int tx = threadIdx.x, ty = threadIdx.y;  // 32 x 8
#pragma unroll
  for (int r = 0; r < 4; ++r)
    tile[ty + r * 8][tx] = W1[(k0 + ty + r * 8) * 512 + n0 + tx];
  __syncthreads();
#pragma unroll
  for (int r = 0; r < 4; ++r)
    W1t[(n0 + ty + r * 8) * 1024 + k0 + tx] = f2bf(tile[tx][ty + r * 8]);
}

// ---------------- proj_gemm ----------------
// Tile 128(M)x128(N), K=512 (16 x BK=32). Wave w owns M rows [w*32,w*32+32).
__global__ __launch_bounds__(256, 2) void proj_gemm(
    const float* __restrict__ hidden,        // [16384][1024]
    const unsigned short* __restrict__ w1t,  // [512][1024] bf16
    unsigned short* __restrict__ UV) {       // [16384][1024] bf16
  __shared__ __align__(16) unsigned short Ab[128 * 40];
  __shared__ __align__(16) unsigned short Bb[128 * 32];
  __shared__ __align__(16) unsigned short Eb[4][32][136];  // epilogue repack
  const int t = threadIdx.x;
  const int lane = t & 63;
  const int w = t >> 6;
  const int r0 = blockIdx.x << 7;
  const int n0 = blockIdx.y << 7;
  const int hk = blockIdx.z << 9;   // 0 (U half) or 512 (V half)

  f32x4 acc[2][8];
#pragma unroll
  for (int i = 0; i < 2; ++i)
#pragma unroll
    for (int j = 0; j < 8; ++j) acc[i][j] = (f32x4){0.f, 0.f, 0.f, 0.f};

  const int ar = t >> 1;            // A stage row 0..127
  const int akc = (t & 1) << 4;     // k offset 0/16
  const float* agp = hidden + (r0 + ar) * 1024 + hk + akc;

  int boff[2];
#pragma unroll
  for (int q = 0; q < 2; ++q) {
    int ln = (w << 5) + (q << 4) + (lane >> 2);
    int sc = (lane & 3) ^ ((ln >> 1) & 3);   // chunk swizzle (write side)
    boff[q] = (n0 + ln) * 1024 + hk + (sc << 3);
  }

  for (int it = 0; it < 16; ++it) {
    const int k0 = it << 5;
#pragma unroll
    for (int q = 0; q < 2; ++q) {
      const unsigned short* gp = w1t + boff[q] + k0;
      unsigned short* lp = &Bb[((w << 5) + (q << 4)) << 5];  // wave-uniform base
      __builtin_amdgcn_global_load_lds(
          (const __attribute__((address_space(1))) void*)gp,
          (__attribute__((address_space(3))) void*)lp, 16, 0, 0);
    }
    {
      const float4* p = (const float4*)(agp + k0);
      float4 a0 = p[0], a1 = p[1], a2 = p[2], a3 = p[3];
      uint4 p0, p1;
      p0.x = (unsigned)f2bf(a0.x) | ((unsigned)f2bf(a0.y) << 16);
      p0.y = (unsigned)f2bf(a0.z) | ((unsigned)f2bf(a0.w) << 16);
      p0.z = (unsigned)f2bf(a1.x) | ((unsigned)f2bf(a1.y) << 16);
      p0.w = (unsigned)f2bf(a1.z) | ((unsigned)f2bf(a1.w) << 16);
      p1.x = (unsigned)f2bf(a2.x) | ((unsigned)f2bf(a2.y) << 16);
      p1.y = (unsigned)f2bf(a2.z) | ((unsigned)f2bf(a2.w) << 16);
      p1.z = (unsigned)f2bf(a3.x) | ((unsigned)f2bf(a3.y) << 16);
      p1.w = (unsigned)f2bf(a3.z) | ((unsigned)f2bf(a3.w) << 16);
      *(uint4*)((char*)Ab + ar * 80 + akc * 2) = p0;
      *(uint4*)((char*)Ab + ar * 80 + akc * 2 + 16) = p1;
    }
    __syncthreads();

    bf16x8 af[2], bfr[8];
#pragma unroll
    for (int mt = 0; mt < 2; ++mt) {
      int row = (w << 5) + (mt << 4) + (lane & 15);
      af[mt] = *(const bf16x8*)((const char*)Ab + row * 80 + ((lane >> 4) << 4));
    }
#pragma unroll
    for (int nt = 0; nt < 8; ++nt) {
      int ln = (nt << 4) + (lane & 15);
      int cs = (lane >> 4) ^ ((ln >> 1) & 3);
      bfr[nt] = *(const bf16x8*)((const char*)Bb + ln * 64 + (cs << 4));
    }
#pragma unroll
    for (int mt = 0; mt < 2; ++mt)
#pragma unroll
      for (int nt = 0; nt < 8; ++nt)
        acc[mt][nt] = __builtin_amdgcn_mfma_f32_16x16x32_bf16(af[mt], bfr[nt],
                                                              acc[mt][nt], 0, 0, 0);
    __syncthreads();
  }

  // Epilogue: wave-local LDS repack (no barrier needed: own region only),
  // then 8 coalesced 16B/lane stores. C/D: col=lane&15, row=(lane>>4)*4+reg.
#pragma unroll
  for (int mt = 0; mt < 2; ++mt)
#pragma unroll
    for (int r = 0; r < 4; ++r) {
      int rr = (mt << 4) + ((lane >> 4) << 2) + r;   // 0..31 in wave band
#pragma unroll
      for (int nt = 0; nt < 8; ++nt)
        Eb[w][rr][(nt << 4) + (lane & 15)] = f2bf(acc[mt][nt][r]);
    }
#pragma unroll
  for (int i = 0; i < 8; ++i) {
    int rr = (lane >> 3) + ((i & 3) << 3);           // 0..31
    int ck = (lane & 7) + ((i >> 2) << 3);           // 0..15 (16B chunks)
    uint4 vv = *(const uint4*)&Eb[w][rr][ck << 3];
    int grow = r0 + (w << 5) + rr;
    *(uint4*)(UV + (grow << 10) + hk + n0 + (ck << 3)) = vv;
  }
}

// ---------------- span_eval: 16 spans per wave, block partials, NO atomics ----
#define SPW 16
__global__ __launch_bounds__(256) void span_eval(
    const unsigned short* __restrict__ UV,
    const int* __restrict__ bids, const int* __restrict__ begins,
    const int* __restrict__ ends, const int* __restrict__ flags,
    const float* __restrict__ weights,
    const float* __restrict__ b1, const float* __restrict__ w2,
    const float* __restrict__ b2, float* __restrict__ partials) {
  __shared__ float red[4][3];
  const int t = threadIdx.x;
  const int lane = t & 63;
  const int w = t >> 6;
  const int sbase = ((blockIdx.x << 2) + w) * SPW;

  // lane l < SPW owns span sbase+l's meta
  int oU1 = 0, oU0 = 0, oVb = 0, oVe = 0, myfl = 0;
  float mywt = 0.f;
  if (lane < SPW) {
    int s = sbase + lane;
    int b = bids[s], bg = begins[s], en = ends[s];
    oU1 = (((en - 1) << 5) + b) << 10;
    oU0 = (((bg - 1) << 5) + b) << 10;
    oVb = ((((bg) << 5) + b) << 10) + 512;
    oVe = ((((en) << 5) + b) << 10) + 512;
    myfl = flags[s];
    mywt = weights[s];
  }

  const int c0 = lane << 3;
  float4 b1a = *(const float4*)(b1 + c0), b1b = *(const float4*)(b1 + c0 + 4);
  float4 w2a = *(const float4*)(w2 + c0), w2b = *(const float4*)(w2 + c0 + 4);
  float b1v[8] = {b1a.x, b1a.y, b1a.z, b1a.w, b1b.x, b1b.y, b1b.z, b1b.w};
  float w2v[8] = {w2a.x, w2a.y, w2a.z, w2a.w, w2b.x, w2b.y, w2b.z, w2b.w};

  bf16x8 cu1, cu0, cvb, cve, nu1, nu0, nvb, nve;
  {
    cu1 = *(const bf16x8*)(UV + __shfl(oU1, 0) + c0);
    cu0 = *(const bf16x8*)(UV + __shfl(oU0, 0) + c0);
    cvb = *(const bf16x8*)(UV + __shfl(oVb, 0) + c0);
    cve = *(const bf16x8*)(UV + __shfl(oVe, 0) + c0);
  }

  float mylogit = 0.f;
#pragma unroll
  for (int j = 0; j < SPW; ++j) {
    if (j + 1 < SPW) {   // prefetch next span (8 loads in flight)
      nu1 = *(const bf16x8*)(UV + __shfl(oU1, j + 1) + c0);
      nu0 = *(const bf16x8*)(UV + __shfl(oU0, j + 1) + c0);
      nvb = *(const bf16x8*)(UV + __shfl(oVb, j + 1) + c0);
      nve = *(const bf16x8*)(UV + __shfl(oVe, j + 1) + c0);
    }
    float sv = 0.f;
#pragma unroll
    for (int k = 0; k < 8; ++k) {
      float zp = (float)cu1[k] - (float)cu0[k] + (float)cvb[k] - (float)cve[k] + b1v[k];
      sv += fmaxf(zp, 0.f) * w2v[k];
    }
#pragma unroll
    for (int off = 1; off < 64; off <<= 1) sv += __shfl_xor(sv, off);
    if (lane == j) mylogit = sv;   // park span j's logit in lane j
    cu1 = nu1; cu0 = nu0; cvb = nvb; cve = nve;
  }

  // lane-parallel sigmoid/BCE for the 16 spans
  float pos_t = 0.f, neg_t = 0.f, cnt_t = 0.f;
  if (lane < SPW) {
    float logit = mylogit + b2[0];
    float p = 1.f / (1.f + expf(-logit));
    p = fminf(fmaxf(p, 1e-7f), 1.f - 1e-7f);
    float bce = (myfl == 1) ? -logf(p) : -logf(1.f - p);
    float term = mywt * bce;
    pos_t = (myfl == 1) ? term : 0.f;
    neg_t = (myfl == 1) ? 0.f : term;
    cnt_t = (myfl == 1) ? 1.f : 0.f;
  }
#pragma unroll
  for (int off = 1; off < 64; off <<= 1) {
    pos_t += __shfl_xor(pos_t, off);
    neg_t += __shfl_xor(neg_t, off);
    cnt_t += __shfl_xor(cnt_t, off);
  }
  if (lane == 0) { red[w][0] = pos_t; red[w][1] = neg_t; red[w][2] = cnt_t; }
  __syncthreads();
  if (t == 0) {
    partials[(blockIdx.x << 2) + 0] = red[0][0] + red[1][0] + red[2][0] + red[3][0];
    partials[(blockIdx.x << 2) + 1] = red[0][1] + red[1][1] + red[2][1] + red[3][1];
    partials[(blockIdx.x << 2) + 2] = red[0][2] + red[1][2] + red[2][2] + red[3][2];
  }
}

// ---------------- finalize: reduce per-block partials ----------------
__global__ void finalize(const float* __restrict__ parts, int nblk,
                         float* __restrict__ out, int nspans) {
  __shared__ float sp[4], sn[4], sc[4];
  float P = 0.f, Ng = 0.f, C = 0.f;
  for (int i = threadIdx.x; i < nblk; i += 256) {
    P += parts[(i << 2) + 0];
    Ng += parts[(i << 2) + 1];
    C += parts[(i << 2) + 2];
  }
#pragma unroll
  for (int off = 1; off < 64; off <<= 1) {
    P += __shfl_xor(P, off);
    Ng += __shfl_xor(Ng, off);
    C += __shfl_xor(C, off);
  }
  int w = threadIdx.x >> 6;
  if ((threadIdx.x & 63) == 0) { sp[w] = P; sn[w] = Ng; sc[w] = C; }
  __syncthreads();
  if (threadIdx.x == 0) {
    P = sp[0] + sp[1] + sp[2] + sp[3];
    Ng = sn[0] + sn[1] + sn[2] + sn[3];
    C = sc[0] + sc[1] + sc[2] + sc[3];
    float scale = 2.f * C / (float)nspans;
    out[0] = (P + scale * Ng) / (float)nspans;
  }
}

extern "C" void kernel_launch(void* const* d_in, const int* in_sizes, int n_in,
                              void* d_out, int out_size, void* d_ws, size_t ws_size,
                              hipStream_t stream) {
  const float* hidden = (const float*)d_in[0];
  const int* bids     = (const int*)d_in[1];
  const int* begins   = (const int*)d_in[2];
  const int* ends     = (const int*)d_in[3];
  const int* flags    = (const int*)d_in[4];
  const float* weights = (const float*)d_in[5];
  const float* W1 = (const float*)d_in[6];
  const float* b1 = (const float*)d_in[7];
  const float* W2 = (const float*)d_in[8];
  const float* b2 = (const float*)d_in[9];
  float* out = (float*)d_out;
  const int nspans = in_sizes[1];  // 131072
  const int nblk = nspans / (4 * SPW);  // 2048 span_eval blocks

  float* partials = (float*)d_ws;                                   // 32 KiB
  unsigned short* W1t = (unsigned short*)((char*)d_ws + (1 << 18)); // 1 MiB
  unsigned short* UV = (unsigned short*)((char*)d_ws + (2 << 20));  // 33.6 MiB

  w1_transpose<<<dim3(32, 16), dim3(32, 8), 0, stream>>>(W1, W1t);
  proj_gemm<<<dim3(128, 4, 2), 256, 0, stream>>>(hidden, W1t, UV);
  span_eval<<<nblk, 256, 0, stream>>>(UV, bids, begins, ends, flags, weights,
                                      b1, W2, b2, partials);
  finalize<<<1, 256, 0, stream>>>(partials, nblk, out, nspans);
}

// Round 5
// 185.826 us; speedup vs baseline: 7.3084x; 1.1830x over previous
//
#include <hip/hip_runtime.h>
#include <hip/hip_bf16.h>

// PhraseClassifier R5.
//   proj_gemm: 64Mx512N tiles (A read ONCE, B L2-resident), bf16 MFMA,
//              epilogue LDS-repack -> fp8-e4m3 UV (halves span_eval bytes).
//   span_eval: one span per half-wave, 512B row loads, fp8 decode,
//              block partials (no atomics) -> finalize.
// Tolerance budget: threshold is 2% relative; fp8 storage of U,V gives
// mean-loss bias ~5e-4 (z-err sigma 0.05 -> logit sigma 0.04, cancels over 131072 spans).

typedef float f32x4 __attribute__((ext_vector_type(4)));
typedef float f32x2 __attribute__((ext_vector_type(2)));
typedef __bf16 bf16x8 __attribute__((ext_vector_type(8)));

__device__ __forceinline__ unsigned short f2bf(float f) {
  unsigned int u = __float_as_uint(f);
  u += 0x7fffu + ((u >> 16) & 1u);   // RNE
  return (unsigned short)(u >> 16);
}
__device__ __forceinline__ float bf2f(unsigned int lo16) {
  return __uint_as_float(lo16 << 16);
}

// ---------------- prep: W1 [1024][512] fp32 -> W1t [512][1024] bf16 ----------------
__global__ void w1_transpose(const float* __restrict__ W1, unsigned short* __restrict__ W1t) {
  __shared__ float tile[32][33];
  int k0 = blockIdx.x * 32, n0 = blockIdx.y * 32;
  int tx = threadIdx.x, ty = threadIdx.y;  // 32 x 8
#pragma unroll
  for (int r = 0; r < 4; ++r)
    tile[ty + r * 8][tx] = W1[(k0 + ty + r * 8) * 512 + n0 + tx];
  __syncthreads();
#pragma unroll
  for (int r = 0; r < 4; ++r)
    W1t[(n0 + ty + r * 8) * 1024 + k0 + tx] = f2bf(tile[tx][ty + r * 8]);
}

// ---------------- proj_gemm: 64M x 512N, K=512 (16 x BK=32) ----------------
// Grid (256, 2): x = M-block, y = half (U: cols 0..511 of hidden & W1 rows 0..511;
// V: +512). Wave w owns cols [w*128, w*128+128): acc 4m x 8n f32x4.
__global__ __launch_bounds__(256, 2) void proj_gemm(
    const float* __restrict__ hidden,        // [16384][1024]
    const unsigned short* __restrict__ w1t,  // [512][1024] bf16
    unsigned char* __restrict__ UVq) {       // [16384][1024] fp8 e4m3
  __shared__ __align__(16) unsigned short Ab[64 * 40];    // 5 KB (+8 pad)
  __shared__ __align__(16) unsigned short Bb[512 * 32];   // 32 KB, chunk-swizzled
  __shared__ __align__(16) unsigned short Eb[4][32][136]; // 34.8 KB epilogue
  const int t = threadIdx.x;
  const int lane = t & 63;
  const int w = t >> 6;
  const int r0 = blockIdx.x << 6;
  const int hk = blockIdx.y << 9;   // 0 (U) or 512 (V)

  f32x4 acc[4][8];
#pragma unroll
  for (int i = 0; i < 4; ++i)
#pragma unroll
    for (int j = 0; j < 8; ++j) acc[i][j] = (f32x4){0.f, 0.f, 0.f, 0.f};

  const int ar = t >> 2;            // A stage: row 0..63 (4 thr/row)
  const int acg = (t & 3) << 3;     // k offset 0/8/16/24
  const float* agp = hidden + (r0 + ar) * 1024 + hk + acg;

  // B: LDS chunk c of row n holds logical chunk c^((n>>1)&3) -> frag reads 2-way max
  int boff[8];
#pragma unroll
  for (int q = 0; q < 8; ++q) {
    int n = (w << 7) + (q << 4) + (lane >> 2);
    int sc = (lane & 3) ^ ((n >> 1) & 3);
    boff[q] = n * 1024 + hk + (sc << 3);
  }

  for (int it = 0; it < 16; ++it) {
    const int k0 = it << 5;
#pragma unroll
    for (int q = 0; q < 8; ++q) {
      const unsigned short* gp = w1t + boff[q] + k0;
      unsigned short* lp = &Bb[((w << 7) + (q << 4)) << 5];  // wave-uniform base
      __builtin_amdgcn_global_load_lds(
          (const __attribute__((address_space(1))) void*)gp,
          (__attribute__((address_space(3))) void*)lp, 16, 0, 0);
    }
    {
      const float4* p = (const float4*)(agp + k0);
      float4 a0 = p[0], a1 = p[1];
      uint4 pk;
      pk.x = (unsigned)f2bf(a0.x) | ((unsigned)f2bf(a0.y) << 16);
      pk.y = (unsigned)f2bf(a0.z) | ((unsigned)f2bf(a0.w) << 16);
      pk.z = (unsigned)f2bf(a1.x) | ((unsigned)f2bf(a1.y) << 16);
      pk.w = (unsigned)f2bf(a1.z) | ((unsigned)f2bf(a1.w) << 16);
      *(uint4*)((char*)Ab + ar * 80 + (t & 3) * 16) = pk;
    }
    __syncthreads();

    bf16x8 af[4], bfr[8];
#pragma unroll
    for (int mt = 0; mt < 4; ++mt) {
      int row = (mt << 4) + (lane & 15);
      af[mt] = *(const bf16x8*)((const char*)Ab + row * 80 + ((lane >> 4) << 4));
    }
#pragma unroll
    for (int nt = 0; nt < 8; ++nt) {
      int n = (w << 7) + (nt << 4) + (lane & 15);
      int cs = (lane >> 4) ^ ((n >> 1) & 3);
      bfr[nt] = *(const bf16x8*)((const char*)Bb + n * 64 + (cs << 4));
    }
#pragma unroll
    for (int mt = 0; mt < 4; ++mt)
#pragma unroll
      for (int nt = 0; nt < 8; ++nt)
        acc[mt][nt] = __builtin_amdgcn_mfma_f32_16x16x32_bf16(af[mt], bfr[nt],
                                                              acc[mt][nt], 0, 0, 0);
    __syncthreads();
  }

  // Epilogue: 2 passes of 32 rows. Repack to row-major bf16 in Eb (wave-local),
  // then coalesced 8B/lane fp8 stores. C/D: col=lane&15, row=(lane>>4)*4+reg.
#pragma unroll
  for (int pass = 0; pass < 2; ++pass) {
#pragma unroll
    for (int mh = 0; mh < 2; ++mh) {
      int mt = (pass << 1) + mh;
#pragma unroll
      for (int r = 0; r < 4; ++r) {
        int rr = (mh << 4) + ((lane >> 4) << 2) + r;   // 0..31
#pragma unroll
        for (int nt = 0; nt < 8; ++nt)
          Eb[w][rr][(nt << 4) + (lane & 15)] = f2bf(acc[mt][nt][r]);
      }
    }
#pragma unroll
    for (int i = 0; i < 8; ++i) {
      int task = (i << 6) + lane;
      int rr = task >> 4;                 // 0..31
      int ck = task & 15;                 // 8-col chunk
      uint4 v = *(const uint4*)&Eb[w][rr][ck << 3];
      float f0 = bf2f(v.x & 0xffff), f1 = bf2f(v.x >> 16);
      float f2 = bf2f(v.y & 0xffff), f3 = bf2f(v.y >> 16);
      float f4 = bf2f(v.z & 0xffff), f5 = bf2f(v.z >> 16);
      float f6 = bf2f(v.w & 0xffff), f7 = bf2f(v.w >> 16);
      uint2 o;
      o.x = __builtin_amdgcn_cvt_pk_fp8_f32(f0, f1, 0, false);
      o.x = __builtin_amdgcn_cvt_pk_fp8_f32(f2, f3, o.x, true);
      o.y = __builtin_amdgcn_cvt_pk_fp8_f32(f4, f5, 0, false);
      o.y = __builtin_amdgcn_cvt_pk_fp8_f32(f6, f7, o.y, true);
      int grow = r0 + (pass << 5) + rr;
      *(uint2*)(UVq + (grow << 10) + hk + (w << 7) + (ck << 3)) = o;
    }
    __syncthreads();   // Eb reuse between passes
  }
}

// ---------------- span_eval: 1 span per half-wave, 16/wave, block partials ----
#define SPW 16
__global__ __launch_bounds__(256) void span_eval(
    const unsigned char* __restrict__ UVq,
    const int* __restrict__ bids, const int* __restrict__ begins,
    const int* __restrict__ ends, const int* __restrict__ flags,
    const float* __restrict__ weights,
    const float* __restrict__ b1, const float* __restrict__ w2,
    const float* __restrict__ b2, float* __restrict__ partials) {
  __shared__ float red[4][3];
  const int t = threadIdx.x;
  const int lane = t & 63;
  const int w = t >> 6;
  const int h = lane >> 5;          // half-wave id
  const int hl = lane & 31;
  const int sbase = ((blockIdx.x << 2) + w) * SPW;

  int oU1 = 0, oU0 = 0, oVb = 0, oVe = 0, myfl = 0;
  float mywt = 0.f;
  if (lane < SPW) {                 // lane l owns span sbase+l's meta
    int s = sbase + lane;
    int b = bids[s], bg = begins[s], en = ends[s];
    oU1 = (((en - 1) << 5) + b) << 10;
    oU0 = (((bg - 1) << 5) + b) << 10;
    oVb = (((bg << 5) + b) << 10) + 512;
    oVe = (((en << 5) + b) << 10) + 512;
    myfl = flags[s];
    mywt = weights[s];
  }

  const int c0 = hl << 4;           // 16 cols per lane, 32 lanes = 512
  float b1v[16], w2v[16];
#pragma unroll
  for (int q = 0; q < 4; ++q) {
    float4 bv = *(const float4*)(b1 + c0 + (q << 2));
    float4 wv = *(const float4*)(w2 + c0 + (q << 2));
    b1v[(q << 2) + 0] = bv.x; b1v[(q << 2) + 1] = bv.y;
    b1v[(q << 2) + 2] = bv.z; b1v[(q << 2) + 3] = bv.w;
    w2v[(q << 2) + 0] = wv.x; w2v[(q << 2) + 1] = wv.y;
    w2v[(q << 2) + 2] = wv.z; w2v[(q << 2) + 3] = wv.w;
  }

  auto dec = [](unsigned int v, float* f) {
    f32x2 a = __builtin_amdgcn_cvt_pk_f32_fp8(v, false);
    f32x2 b = __builtin_amdgcn_cvt_pk_f32_fp8(v, true);
    f[0] = a[0]; f[1] = a[1]; f[2] = b[0]; f[3] = b[1];
  };

  uint4 cu1, cu0, cvb, cve, nu1, nu0, nvb, nve;
  {
    int src = h << 3;
    cu1 = *(const uint4*)(UVq + __shfl(oU1, src) + c0);
    cu0 = *(const uint4*)(UVq + __shfl(oU0, src) + c0);
    cvb = *(const uint4*)(UVq + __shfl(oVb, src) + c0);
    cve = *(const uint4*)(UVq + __shfl(oVe, src) + c0);
  }

  float mylogit = 0.f;
#pragma unroll
  for (int j = 0; j < 8; ++j) {
    if (j + 1 < 8) {
      int src = (h << 3) + j + 1;
      nu1 = *(const uint4*)(UVq + __shfl(oU1, src) + c0);
      nu0 = *(const uint4*)(UVq + __shfl(oU0, src) + c0);
      nvb = *(const uint4*)(UVq + __shfl(oVb, src) + c0);
      nve = *(const uint4*)(UVq + __shfl(oVe, src) + c0);
    }
    float u1f[16], u0f[16], vbf[16], vef[16];
    dec(cu1.x, u1f); dec(cu1.y, u1f + 4); dec(cu1.z, u1f + 8); dec(cu1.w, u1f + 12);
    dec(cu0.x, u0f); dec(cu0.y, u0f + 4); dec(cu0.z, u0f + 8); dec(cu0.w, u0f + 12);
    dec(cvb.x, vbf); dec(cvb.y, vbf + 4); dec(cvb.z, vbf + 8); dec(cvb.w, vbf + 12);
    dec(cve.x, vef); dec(cve.y, vef + 4); dec(cve.z, vef + 8); dec(cve.w, vef + 12);
    float sv = 0.f;
#pragma unroll
    for (int k = 0; k < 16; ++k) {
      float zp = u1f[k] - u0f[k] + vbf[k] - vef[k] + b1v[k];
      sv += fmaxf(zp, 0.f) * w2v[k];
    }
    sv += __shfl_xor(sv, 1);
    sv += __shfl_xor(sv, 2);
    sv += __shfl_xor(sv, 4);
    sv += __shfl_xor(sv, 8);
    sv += __shfl_xor(sv, 16);       // reduce within half-wave
    if (hl == j) mylogit = sv;      // lane h*32+j parks span h*8+j
    cu1 = nu1; cu0 = nu0; cvb = nvb; cve = nve;
  }

  // move parked logits to lanes 0..15 (span l from lane ((l&8)<<2)+(l&7))
  mylogit = __shfl(mylogit, ((lane & 8) << 2) + (lane & 7));

  float pos_t = 0.f, neg_t = 0.f, cnt_t = 0.f;
  if (lane < SPW) {
    float logit = mylogit + b2[0];
    float p = 1.f / (1.f + expf(-logit));
    p = fminf(fmaxf(p, 1e-7f), 1.f - 1e-7f);
    float bce = (myfl == 1) ? -logf(p) : -logf(1.f - p);
    float term = mywt * bce;
    pos_t = (myfl == 1) ? term : 0.f;
    neg_t = (myfl == 1) ? 0.f : term;
    cnt_t = (myfl == 1) ? 1.f : 0.f;
  }
#pragma unroll
  for (int off = 1; off < 64; off <<= 1) {
    pos_t += __shfl_xor(pos_t, off);
    neg_t += __shfl_xor(neg_t, off);
    cnt_t += __shfl_xor(cnt_t, off);
  }
  if (lane == 0) { red[w][0] = pos_t; red[w][1] = neg_t; red[w][2] = cnt_t; }
  __syncthreads();
  if (t == 0) {
    partials[(blockIdx.x << 2) + 0] = red[0][0] + red[1][0] + red[2][0] + red[3][0];
    partials[(blockIdx.x << 2) + 1] = red[0][1] + red[1][1] + red[2][1] + red[3][1];
    partials[(blockIdx.x << 2) + 2] = red[0][2] + red[1][2] + red[2][2] + red[3][2];
  }
}

// ---------------- finalize ----------------
__global__ void finalize(const float* __restrict__ parts, int nblk,
                         float* __restrict__ out, int nspans) {
  __shared__ float sp[4], sn[4], sc[4];
  float P = 0.f, Ng = 0.f, C = 0.f;
  for (int i = threadIdx.x; i < nblk; i += 256) {
    P += parts[(i << 2) + 0];
    Ng += parts[(i << 2) + 1];
    C += parts[(i << 2) + 2];
  }
#pragma unroll
  for (int off = 1; off < 64; off <<= 1) {
    P += __shfl_xor(P, off);
    Ng += __shfl_xor(Ng, off);
    C += __shfl_xor(C, off);
  }
  int w = threadIdx.x >> 6;
  if ((threadIdx.x & 63) == 0) { sp[w] = P; sn[w] = Ng; sc[w] = C; }
  __syncthreads();
  if (threadIdx.x == 0) {
    P = sp[0] + sp[1] + sp[2] + sp[3];
    Ng = sn[0] + sn[1] + sn[2] + sn[3];
    C = sc[0] + sc[1] + sc[2] + sc[3];
    float scale = 2.f * C / (float)nspans;
    out[0] = (P + scale * Ng) / (float)nspans;
  }
}

extern "C" void kernel_launch(void* const* d_in, const int* in_sizes, int n_in,
                              void* d_out, int out_size, void* d_ws, size_t ws_size,
                              hipStream_t stream) {
  const float* hidden = (const float*)d_in[0];
  const int* bids     = (const int*)d_in[1];
  const int* begins   = (const int*)d_in[2];
  const int* ends     = (const int*)d_in[3];
  const int* flags    = (const int*)d_in[4];
  const float* weights = (const float*)d_in[5];
  const float* W1 = (const float*)d_in[6];
  const float* b1 = (const float*)d_in[7];
  const float* W2 = (const float*)d_in[8];
  const float* b2 = (const float*)d_in[9];
  float* out = (float*)d_out;
  const int nspans = in_sizes[1];       // 131072
  const int nblk = nspans / (4 * SPW);  // 2048

  float* partials = (float*)d_ws;                                    // 32 KiB
  unsigned short* W1t = (unsigned short*)((char*)d_ws + (1 << 18));  // 1 MiB
  unsigned char* UVq = (unsigned char*)((char*)d_ws + (2 << 20));    // 16.8 MiB

  w1_transpose<<<dim3(32, 16), dim3(32, 8), 0, stream>>>(W1, W1t);
  proj_gemm<<<dim3(256, 2), 256, 0, stream>>>(hidden, W1t, UVq);
  span_eval<<<nblk, 256, 0, stream>>>(UVq, bids, begins, ends, flags, weights,
                                      b1, W2, b2, partials);
  finalize<<<1, 256, 0, stream>>>(partials, nblk, out, nspans);
}